// Round 5
// baseline (393.996 us; speedup 1.0000x reference)
//
#include <hip/hip_runtime.h>

// Quantized (int4-packed) embedding bag, sum mode, output [B, 3*D] = [eb|eb|other].
// V=1e6, D=128, B=16384, L=50. weights: [V, D/2] int32; each int32 holds ONE byte
// (two nibbles -> 2 output cols) -> 4x storage inflation.
//
// R5: two phases.
//  Phase 1: repack table into d_ws: [V][16] dwords (4 code bytes per dword),
//           row = 64 B = ONE cacheline. Streaming, coalesced: 256MB rd + 64MB wr.
//  Phase 2: gather from packed table. One wave per bag; lane l: g=l>>4 (row
//           group), t=l&15 (dword t -> cols 8t..8t+7). One 4B load per lane
//           covers 4 rows/wave -> 4x fewer L2 line requests than R4, and the
//           64MB packed table is L3-resident. (R4 post-mortem: gather is
//           outstanding-request-rate limited, not MLP-limited.)

#define DIM 128

__global__ __launch_bounds__(256) void repack_kernel(
    const uint4* __restrict__ weights,   // [V*16] uint4 (= [V][64] dwords)
    unsigned* __restrict__ packed,       // [V*16] dwords out
    int n) {                             // n = V*16
  int i = blockIdx.x * 256 + threadIdx.x;
  if (i >= n) return;
  const uint4 w = weights[i];            // 16B/lane, fully coalesced
  packed[i] = (w.x & 0xFFu) | ((w.y & 0xFFu) << 8) |
              ((w.z & 0xFFu) << 16) | ((w.w & 0xFFu) << 24);
}

__global__ __launch_bounds__(256) void qebag_kernel(
    const unsigned* __restrict__ packed,    // [V][16] dwords (64B rows)
    const float* __restrict__ scales,       // [V]
    const float* __restrict__ zeros,        // [V]
    const int* __restrict__ indices,        // [N]
    const int* __restrict__ offsets,        // [B+1]
    const float* __restrict__ other,        // [B, 128]
    float* __restrict__ out,                // [B, 384]
    int B) {
  const int wave = threadIdx.x >> 6;
  const int lane = threadIdx.x & 63;
  const int g = lane >> 4;   // row-group 0..3
  const int t = lane & 15;   // dword t -> cols [8t, 8t+8)
  int bag = blockIdx.x * 4 + wave;
  if (bag >= B) return;
  bag = __builtin_amdgcn_readfirstlane(bag);  // uniform -> s_load for offsets

  const int start = offsets[bag];
  const int count = offsets[bag + 1] - start;  // 50 here; keep generic

  // Prefetch `other` passthrough (lanes 32..63 own it in the epilogue).
  const float4* oth4 = (const float4*)(other + (size_t)bag * DIM);
  float4 oth = make_float4(0.f, 0.f, 0.f, 0.f);
  if (lane >= 32) oth = oth4[lane - 32];

  float acc[8];
  #pragma unroll
  for (int k = 0; k < 8; ++k) acc[k] = 0.f;
  float corr = 0.f;  // sum(s*z) over the bag

  for (int base = 0; base < count; base += 64) {
    const int cnt = min(64, count - base);

    // parallel metadata gather: lane j owns bag-row (base+j); pad beyond cnt
    int idx = 0; float s = 0.f, sz = 0.f;
    if (lane < cnt) {
      idx = indices[start + base + lane];   // coalesced
      s = scales[idx];                      // random gather (4MB, L3-warm)
      sz = s * zeros[idx];
    }
    float c = sz;                           // butterfly: corr in all lanes
    #pragma unroll
    for (int off = 1; off < 64; off <<= 1) c += __shfl_xor(c, off);
    corr += c;

    // ---- straight-line burst: 16 quads cover rows 0..63 of this chunk ----
    int ij[16]; float sj[16];
    #pragma unroll
    for (int i = 0; i < 16; ++i) {
      const int src = 4 * i + g;            // padded lanes give idx=0, s=0
      ij[i] = __shfl(idx, src);
      sj[i] = __shfl(s, src);
    }
    unsigned w[16];
    #pragma unroll
    for (int i = 0; i < 16; ++i)
      w[i] = packed[(size_t)(unsigned)ij[i] * 16 + t];  // 64B/row, 1 line/row
    #pragma unroll
    for (int i = 0; i < 16; ++i) {
      acc[0] = fmaf(sj[i], (float)(w[i] & 0xFu), acc[0]);
      acc[1] = fmaf(sj[i], (float)((w[i] >> 4) & 0xFu), acc[1]);
      acc[2] = fmaf(sj[i], (float)((w[i] >> 8) & 0xFu), acc[2]);
      acc[3] = fmaf(sj[i], (float)((w[i] >> 12) & 0xFu), acc[3]);
      acc[4] = fmaf(sj[i], (float)((w[i] >> 16) & 0xFu), acc[4]);
      acc[5] = fmaf(sj[i], (float)((w[i] >> 20) & 0xFu), acc[5]);
      acc[6] = fmaf(sj[i], (float)((w[i] >> 24) & 0xFu), acc[6]);
      acc[7] = fmaf(sj[i], (float)((w[i] >> 28) & 0xFu), acc[7]);
    }
  }

  // reduce the 4 row-groups (lane bits 4,5); all lanes end with full sums
  #pragma unroll
  for (int k = 0; k < 8; ++k) {
    acc[k] += __shfl_xor(acc[k], 16);
    acc[k] += __shfl_xor(acc[k], 32);
    acc[k] -= corr;
  }

  float4* o4 = (float4*)(out + (size_t)bag * (3 * DIM));
  if (g < 2) {
    // groups 0,1 write the two identical eb blocks (cols [0,128) and [128,256))
    const float4 lo = make_float4(acc[0], acc[1], acc[2], acc[3]);
    const float4 hi = make_float4(acc[4], acc[5], acc[6], acc[7]);
    o4[g * 32 + 2 * t]     = lo;
    o4[g * 32 + 2 * t + 1] = hi;
  } else {
    // groups 2,3 copy other_tensor into cols [256,384)
    o4[64 + (lane - 32)] = oth;
  }
}

extern "C" void kernel_launch(void* const* d_in, const int* in_sizes, int n_in,
                              void* d_out, int out_size, void* d_ws, size_t ws_size,
                              hipStream_t stream) {
  const uint4* weights  = (const uint4*)d_in[0];
  const float* scales   = (const float*)d_in[1];
  const float* zeros    = (const float*)d_in[2];
  const int* indices    = (const int*)d_in[3];
  const int* offsets    = (const int*)d_in[4];
  const float* other    = (const float*)d_in[5];
  float* out            = (float*)d_out;
  unsigned* packed      = (unsigned*)d_ws;   // V*16 dwords = 64 MB

  const int B = in_sizes[5] / DIM;           // other_tensor is [B, 128]
  const int npack = in_sizes[0] / 4;         // V*16 packed dwords

  repack_kernel<<<(npack + 255) / 256, 256, 0, stream>>>(weights, packed, npack);

  const int blocks = (B + 3) / 4;            // 4 waves (bags) per 256-thread block
  qebag_kernel<<<blocks, 256, 0, stream>>>(packed, scales, zeros, indices,
                                           offsets, other, out, B);
}

// Round 6
// 350.913 us; speedup vs baseline: 1.1228x; 1.1228x over previous
//
#include <hip/hip_runtime.h>

// Quantized (int4-packed) embedding bag, sum mode, output [B, 3*D] = [eb|eb|other].
// V=1e6, D=128, B=16384, L=50. weights: [V, D/2] int32; each int32 holds ONE byte
// (two nibbles -> 2 output cols). Row = 64 dwords = 256 B.
//
// R6: direct gather (repack reverted: cost 49us, saved ~5 -- gather time tracks
// ROW COUNT, not bytes/lines). Quad-row scheme: lane l -> g=l>>4 (row 4i+g),
// t=l&15 (dwords 4t..4t+3 -> cols 8t..8t+7). Burst split into two half-bursts
// of 8 quads (peak 32 in-flight VGPRs) + __launch_bounds__(256,5) to push
// occupancy 3->5 waves/SIMD: tests whether the ~75 cyc/row/CU serialization is
// overlappable latency (TLP-bound) or a hard per-CU request-path wall.

#define DIM 128

__global__ __launch_bounds__(256, 5) void qebag_kernel(
    const uint4* __restrict__ weights,      // [V, 16] viewed as uint4
    const float* __restrict__ scales,       // [V]
    const float* __restrict__ zeros,        // [V]
    const int* __restrict__ indices,        // [N]
    const int* __restrict__ offsets,        // [B+1]
    const float* __restrict__ other,        // [B, 128]
    float* __restrict__ out,                // [B, 384]
    int B) {
  const int wave = threadIdx.x >> 6;
  const int lane = threadIdx.x & 63;
  const int g = lane >> 4;   // row-group 0..3
  const int t = lane & 15;   // sublane -> cols [8t, 8t+8)
  int bag = blockIdx.x * 4 + wave;
  if (bag >= B) return;
  bag = __builtin_amdgcn_readfirstlane(bag);  // uniform -> s_load for offsets

  const int start = offsets[bag];
  const int count = offsets[bag + 1] - start;  // 50 here; keep generic

  // Prefetch `other` passthrough (lanes 32..63 own it in the epilogue).
  const float4* oth4 = (const float4*)(other + (size_t)bag * DIM);
  float4 oth = make_float4(0.f, 0.f, 0.f, 0.f);
  if (lane >= 32) oth = oth4[lane - 32];

  float acc[8];
  #pragma unroll
  for (int k = 0; k < 8; ++k) acc[k] = 0.f;
  float corr = 0.f;  // sum(s*z) over the bag

  for (int base = 0; base < count; base += 64) {
    const int cnt = min(64, count - base);

    // parallel metadata gather: lane j owns bag-row (base+j); pad beyond cnt
    int idx = 0; float s = 0.f, sz = 0.f;
    if (lane < cnt) {
      idx = indices[start + base + lane];   // coalesced
      s = scales[idx];                      // random gather (4MB, L2/L3-warm)
      sz = s * zeros[idx];
    }
    float c = sz;                           // butterfly: corr in all lanes
    #pragma unroll
    for (int off = 1; off < 64; off <<= 1) c += __shfl_xor(c, off);
    corr += c;

    // two half-bursts of 8 quads: rows [32h, 32h+32) of this chunk
    for (int h = 0; h < 2; ++h) {
      int ij[8]; float sj[8];
      #pragma unroll
      for (int i = 0; i < 8; ++i) {
        const int src = 32 * h + 4 * i + g;   // padded lanes give idx=0, s=0
        ij[i] = __shfl(idx, src);
        sj[i] = __shfl(s, src);
      }
      uint4 w[8];
      #pragma unroll
      for (int i = 0; i < 8; ++i)
        w[i] = weights[(size_t)(unsigned)ij[i] * 16 + t];  // 1KB/wave each
      #pragma unroll
      for (int i = 0; i < 8; ++i) {
        acc[0] = fmaf(sj[i], (float)(w[i].x & 0xFu), acc[0]);
        acc[1] = fmaf(sj[i], (float)((w[i].x >> 4) & 0xFu), acc[1]);
        acc[2] = fmaf(sj[i], (float)(w[i].y & 0xFu), acc[2]);
        acc[3] = fmaf(sj[i], (float)((w[i].y >> 4) & 0xFu), acc[3]);
        acc[4] = fmaf(sj[i], (float)(w[i].z & 0xFu), acc[4]);
        acc[5] = fmaf(sj[i], (float)((w[i].z >> 4) & 0xFu), acc[5]);
        acc[6] = fmaf(sj[i], (float)(w[i].w & 0xFu), acc[6]);
        acc[7] = fmaf(sj[i], (float)((w[i].w >> 4) & 0xFu), acc[7]);
      }
    }
  }

  // reduce the 4 row-groups (lane bits 4,5); all lanes end with full sums
  #pragma unroll
  for (int k = 0; k < 8; ++k) {
    acc[k] += __shfl_xor(acc[k], 16);
    acc[k] += __shfl_xor(acc[k], 32);
    acc[k] -= corr;
  }

  float4* o4 = (float4*)(out + (size_t)bag * (3 * DIM));
  if (g < 2) {
    // groups 0,1 write the two identical eb blocks (cols [0,128) and [128,256))
    const float4 lo = make_float4(acc[0], acc[1], acc[2], acc[3]);
    const float4 hi = make_float4(acc[4], acc[5], acc[6], acc[7]);
    o4[g * 32 + 2 * t]     = lo;
    o4[g * 32 + 2 * t + 1] = hi;
  } else {
    // groups 2,3 copy other_tensor into cols [256,384)
    o4[64 + (lane - 32)] = oth;
  }
}

extern "C" void kernel_launch(void* const* d_in, const int* in_sizes, int n_in,
                              void* d_out, int out_size, void* d_ws, size_t ws_size,
                              hipStream_t stream) {
  const uint4* weights  = (const uint4*)d_in[0];
  const float* scales   = (const float*)d_in[1];
  const float* zeros    = (const float*)d_in[2];
  const int* indices    = (const int*)d_in[3];
  const int* offsets    = (const int*)d_in[4];
  const float* other    = (const float*)d_in[5];
  float* out            = (float*)d_out;

  const int B = in_sizes[5] / DIM;   // other_tensor is [B, 128]
  const int blocks = (B + 3) / 4;    // 4 waves (bags) per 256-thread block

  qebag_kernel<<<blocks, 256, 0, stream>>>(weights, scales, zeros, indices,
                                           offsets, other, out, B);
}